// Round 4
// baseline (254.986 us; speedup 1.0000x reference)
//
#include <hip/hip_runtime.h>

#define N_PIX   32768
#define DIM     64
#define K_CODES 1024
#define NCHUNK  8
#define CHUNK   (K_CODES / NCHUNK)   // 128

// ws layout:
//   [0, 4096)                       : c2[1024] (float)
//   [4096, 4096 + 2 MiB)            : partials float2[NCHUNK][N_PIX]
//   [4096 + 2 MiB, + 128 KiB)       : idx[N_PIX] (int)

__global__ __launch_bounds__(256) void c2_kernel(const float* __restrict__ cb,
                                                 float* __restrict__ c2) {
    int k = blockIdx.x * 256 + threadIdx.x;
    if (k >= K_CODES) return;
    const float* row = cb + k * DIM;
    float a0 = 0.f, a1 = 0.f, a2 = 0.f, a3 = 0.f;
#pragma unroll
    for (int d = 0; d < DIM; d += 4) {
        a0 = fmaf(row[d + 0], row[d + 0], a0);
        a1 = fmaf(row[d + 1], row[d + 1], a1);
        a2 = fmaf(row[d + 2], row[d + 2], a2);
        a3 = fmaf(row[d + 3], row[d + 3], a3);
    }
    c2[k] = (a0 + a1) + (a2 + a3);
}

// One thread = one pixel (P=1, xv[64] fits registers: ~110 VGPR total).
// One block = 256 pixels x 128 codes, codebook chunk staged in LDS (32 KB).
// Inner loop reads rows via uniform-address ds_read_b128 (broadcast, no SGPR
// serialization — round 2/3 were stuck at 85 us on s_load latency, SGPR=112
// can't double-buffer a 64-SGPR row). grid = 128 * 8 = 1024 blocks, 4/CU.
__global__ __launch_bounds__(256, 4) void argmin_lds(const float* __restrict__ x,
                                                     const float* __restrict__ cb,
                                                     const float* __restrict__ c2,
                                                     float2* __restrict__ part) {
    __shared__ alignas(16) float lds_cb[CHUNK][DIM];   // 32 KB
    __shared__ float lds_c2[CHUNK];                    // 512 B

    int blk    = blockIdx.x;
    int pixblk = blk >> 3;       // 0..127
    int chunk  = blk & 7;        // 0..7
    int t  = threadIdx.x;
    int k0 = chunk * CHUNK;

    // Stage codebook chunk: 2048 float4s, 8 per thread, coalesced.
    {
        const float4* cb4  = reinterpret_cast<const float4*>(cb) + (size_t)k0 * (DIM / 4);
        float4*       lds4 = reinterpret_cast<float4*>(&lds_cb[0][0]);
#pragma unroll
        for (int i = 0; i < (CHUNK * DIM / 4) / 256; ++i)
            lds4[t + i * 256] = cb4[t + i * 256];
        if (t < CHUNK) lds_c2[t] = c2[k0 + t];
    }

    int p  = pixblk * 256 + t;   // pixel id in [0, 32768)
    int bb = p >> 10;            // batch
    int hw = p & 1023;           // h*32+w

    // x is [B, D, H, W]: element (bb, d, hw) at bb*DIM*1024 + d*1024 + hw.
    const float* xbase = x + (size_t)bb * (DIM * 1024) + hw;
    float xv[DIM];
#pragma unroll
    for (int d = 0; d < DIM; ++d) xv[d] = xbase[(size_t)d << 10];

    // x2 — same tree as the verified round-2 kernel.
    float s0 = 0.f, s1 = 0.f, s2 = 0.f, s3 = 0.f;
#pragma unroll
    for (int d = 0; d < DIM; d += 4) {
        s0 = fmaf(xv[d + 0], xv[d + 0], s0);
        s1 = fmaf(xv[d + 1], xv[d + 1], s1);
        s2 = fmaf(xv[d + 2], xv[d + 2], s2);
        s3 = fmaf(xv[d + 3], xv[d + 3], s3);
    }
    float x2 = (s0 + s1) + (s2 + s3);

    __syncthreads();

    float best = 1e30f;
    int   bidx = 0;
#pragma unroll 2
    for (int kk = 0; kk < CHUNK; ++kk) {
        const float* crow = &lds_cb[kk][0];   // uniform addr -> broadcast reads
        float c2k = lds_c2[kk];
        float a0 = 0.f, a1 = 0.f, a2 = 0.f, a3 = 0.f;
#pragma unroll
        for (int d = 0; d < DIM; d += 4) {
            // float4 LDS read: ds_read_b128, uniform address, conflict-free
            float4 w = *reinterpret_cast<const float4*>(crow + d);
            a0 = fmaf(xv[d + 0], w.x, a0);
            a1 = fmaf(xv[d + 1], w.y, a1);
            a2 = fmaf(xv[d + 2], w.z, a2);
            a3 = fmaf(xv[d + 3], w.w, a3);
        }
        float dot = (a0 + a1) + (a2 + a3);
        // Reference rounding structure: d2 = (x2 - 2*dot) + c2 (ulp-64 grid
        // quantization stabilizes tie-breaking — verified exact, rounds 2-3).
        float u    = x2 - 2.0f * dot;   // fma contraction safe: 2*dot exact
        float dist = u + c2k;
        int   k    = k0 + kk;
        if (dist < best) { best = dist; bidx = k; }   // strict <: first-min ties
    }
    float2 r;
    r.x = best;
    r.y = __int_as_float(bidx);
    part[(size_t)chunk * N_PIX + p] = r;   // coalesced
}

// Reduce the 8 partials per pixel (ascending chunk, strict < -> first-min),
// store idx, and write quantized [B, D, H, W].
// grid = N_PIX/128 = 256 blocks x 128 threads.
__global__ __launch_bounds__(128) void reduce_quant(const float* __restrict__ cb,
                                                    const float2* __restrict__ part,
                                                    int* __restrict__ idx,
                                                    float* __restrict__ quant) {
    int n = blockIdx.x * 128 + threadIdx.x;
    float best = 1e30f;
    int   bi = 0;
#pragma unroll
    for (int c = 0; c < NCHUNK; ++c) {
        float2 r = part[(size_t)c * N_PIX + n];
        if (r.x < best) { best = r.x; bi = __float_as_int(r.y); }
    }
    idx[n] = bi;

    int bb = n >> 10;
    int hw = n & 1023;
    const float4* crow = reinterpret_cast<const float4*>(cb + (size_t)bi * DIM);
    float* qb = quant + (size_t)bb * (DIM * 1024) + hw;
#pragma unroll
    for (int dq = 0; dq < 16; ++dq) {
        float4 cv = crow[dq];            // L2-resident gather
        qb[(size_t)(dq * 4 + 0) << 10] = cv.x;   // consecutive hw lanes -> coalesced
        qb[(size_t)(dq * 4 + 1) << 10] = cv.y;
        qb[(size_t)(dq * 4 + 2) << 10] = cv.z;
        qb[(size_t)(dq * 4 + 3) << 10] = cv.w;
    }
}

// Pure streaming one-hot writer: flat float4 index e covers enc[n][j0..j0+3]
// with n = e>>8, j0 = (e&255)*4. grid-stride, 2048 blocks.
__global__ __launch_bounds__(256) void enc_write(const int* __restrict__ idx,
                                                 float* __restrict__ enc) {
    const int TOT = (N_PIX / 4) * K_CODES;   // 8388608 float4s
    int tid = blockIdx.x * 256 + threadIdx.x;
    float4* enc4 = reinterpret_cast<float4*>(enc);
    for (int e = tid; e < TOT; e += 2048 * 256) {
        int n  = e >> 8;
        int j0 = (e & 255) << 2;
        int ir = idx[n];                 // row-uniform -> L1/L2 broadcast
        float4 v;
        v.x = (ir == j0 + 0) ? 1.0f : 0.0f;
        v.y = (ir == j0 + 1) ? 1.0f : 0.0f;
        v.z = (ir == j0 + 2) ? 1.0f : 0.0f;
        v.w = (ir == j0 + 3) ? 1.0f : 0.0f;
        enc4[e] = v;
    }
}

extern "C" void kernel_launch(void* const* d_in, const int* in_sizes, int n_in,
                              void* d_out, int out_size, void* d_ws, size_t ws_size,
                              hipStream_t stream) {
    const float* x  = (const float*)d_in[0];
    const float* cb = (const float*)d_in[1];

    float*  c2   = (float*)d_ws;
    float2* part = (float2*)((char*)d_ws + 4096);
    int*    idx  = (int*)((char*)d_ws + 4096 + (size_t)NCHUNK * N_PIX * 8);

    float* enc   = (float*)d_out;                           // [32768, 1024]
    float* quant = (float*)d_out + (size_t)N_PIX * K_CODES; // [32, 64, 32, 32]

    c2_kernel<<<K_CODES / 256, 256, 0, stream>>>(cb, c2);
    argmin_lds<<<(N_PIX / 256) * NCHUNK, 256, 0, stream>>>(x, cb, c2, part);
    reduce_quant<<<N_PIX / 128, 128, 0, stream>>>(cb, part, idx, quant);
    enc_write<<<2048, 256, 0, stream>>>(idx, enc);
}